// Round 1
// baseline (485.851 us; speedup 1.0000x reference)
//
#include <hip/hip_runtime.h>

typedef short s16x8 __attribute__((ext_vector_type(8)));
typedef float f32x4 __attribute__((ext_vector_type(4)));

__device__ __forceinline__ unsigned short f2bf(float f) {
    union { float f; unsigned u; } v; v.f = f;
    return (unsigned short)((v.u + 0x7FFFu + ((v.u >> 16) & 1u)) >> 16);
}
__device__ __forceinline__ float bf2f(unsigned short h) {
    union { unsigned u; float f; } v; v.u = ((unsigned)h) << 16;
    return v.f;
}

#define NBLK 2048   // 16384 positions / 8 per block

__global__ __launch_bounds__(512, 2)
void fused_embed(const float* __restrict__ net_in, const float* __restrict__ embeds,
                 const float* __restrict__ mg, const float* __restrict__ W1,
                 const float* __restrict__ b1, const float* __restrict__ Wf,
                 const float* __restrict__ bfv, const float* __restrict__ gam,
                 const float* __restrict__ bet, float* __restrict__ out)
{
    // LDS: 20480 + 40960 + 66560 + 8448 + 8448 + 32 = 144928 B (<160K)
    __shared__ unsigned short Abuf[2][128][40];   // net_in chunk, bf16, pad->stride 20 dwords (2-way free)
    __shared__ unsigned short WTb[2][256][40];    // W1^T / Wf^T chunk, bf16
    __shared__ unsigned short Hbuf[128][260];     // H = relu(A@W1+b1), bf16
    __shared__ unsigned short gbuf[16][264];      // g rows (8 used + 8 zero pad), bf16
    __shared__ float updb[8][264];                // updates (positions x 256), f32
    __shared__ float sbuf[8];                     // s_p = sum_k w_k m_k

    const int tid  = threadIdx.x;
    const int lane = tid & 63;
    const int wid  = tid >> 6;     // 0..7
    const int wr   = wid >> 2;     // 0..1
    const int wc   = wid & 3;      // 0..3
    const int l15  = lane & 15;
    const int g8   = (lane >> 4) * 8;
    const int blk  = blockIdx.x;
    const int row0 = blk * 128;

    const f32x4 zero4 = {0.f, 0.f, 0.f, 0.f};

    // ================= GEMM1: H = relu(net_in @ W1 + b1) =================
    f32x4 acc[4][4];
    #pragma unroll
    for (int i = 0; i < 4; ++i)
        #pragma unroll
        for (int j = 0; j < 4; ++j)
            acc[i][j] = zero4;

    float4 ra[2], rw[4];
    // prologue: stage chunk 0 into buffer 0
    #pragma unroll
    for (int it = 0; it < 2; ++it) {
        int fl = tid + it * 512;
        ra[it] = *(const float4*)&net_in[(row0 + (fl >> 3)) * 512 + (fl & 7) * 4];
    }
    #pragma unroll
    for (int it = 0; it < 4; ++it) {
        int fl = tid + it * 512;
        rw[it] = *(const float4*)&W1[(fl >> 6) * 256 + (fl & 63) * 4];
    }
    #pragma unroll
    for (int it = 0; it < 2; ++it) {
        int fl = tid + it * 512;
        unsigned short* d = &Abuf[0][fl >> 3][(fl & 7) * 4];
        d[0] = f2bf(ra[it].x); d[1] = f2bf(ra[it].y); d[2] = f2bf(ra[it].z); d[3] = f2bf(ra[it].w);
    }
    #pragma unroll
    for (int it = 0; it < 4; ++it) {
        int fl = tid + it * 512;
        int n4 = (fl & 63) * 4, kl = fl >> 6;
        WTb[0][n4 + 0][kl] = f2bf(rw[it].x);
        WTb[0][n4 + 1][kl] = f2bf(rw[it].y);
        WTb[0][n4 + 2][kl] = f2bf(rw[it].z);
        WTb[0][n4 + 3][kl] = f2bf(rw[it].w);
    }
    __syncthreads();

    for (int kc = 0; kc < 16; ++kc) {
        const int cur = kc & 1;
        // issue next chunk's global loads early (latency hides under MFMA)
        if (kc < 15) {
            #pragma unroll
            for (int it = 0; it < 2; ++it) {
                int fl = tid + it * 512;
                ra[it] = *(const float4*)&net_in[(row0 + (fl >> 3)) * 512 + (kc + 1) * 32 + (fl & 7) * 4];
            }
            #pragma unroll
            for (int it = 0; it < 4; ++it) {
                int fl = tid + it * 512;
                rw[it] = *(const float4*)&W1[((kc + 1) * 32 + (fl >> 6)) * 256 + (fl & 63) * 4];
            }
        }
        // fragments + 16 MFMAs on current buffer
        s16x8 af[4], bfr[4];
        #pragma unroll
        for (int i = 0; i < 4; ++i)
            af[i] = *(const s16x8*)&Abuf[cur][(wr * 4 + i) * 16 + l15][g8];
        #pragma unroll
        for (int j = 0; j < 4; ++j)
            bfr[j] = *(const s16x8*)&WTb[cur][(wc * 4 + j) * 16 + l15][g8];
        #pragma unroll
        for (int i = 0; i < 4; ++i)
            #pragma unroll
            for (int j = 0; j < 4; ++j)
                acc[i][j] = __builtin_amdgcn_mfma_f32_16x16x32_bf16(af[i], bfr[j], acc[i][j], 0, 0, 0);
        // write next chunk into the other buffer
        if (kc < 15) {
            #pragma unroll
            for (int it = 0; it < 2; ++it) {
                int fl = tid + it * 512;
                unsigned short* d = &Abuf[cur ^ 1][fl >> 3][(fl & 7) * 4];
                d[0] = f2bf(ra[it].x); d[1] = f2bf(ra[it].y); d[2] = f2bf(ra[it].z); d[3] = f2bf(ra[it].w);
            }
            #pragma unroll
            for (int it = 0; it < 4; ++it) {
                int fl = tid + it * 512;
                int n4 = (fl & 63) * 4, kl = fl >> 6;
                WTb[cur ^ 1][n4 + 0][kl] = f2bf(rw[it].x);
                WTb[cur ^ 1][n4 + 1][kl] = f2bf(rw[it].y);
                WTb[cur ^ 1][n4 + 2][kl] = f2bf(rw[it].z);
                WTb[cur ^ 1][n4 + 3][kl] = f2bf(rw[it].w);
            }
        }
        __syncthreads();
    }

    // epilogue: H = relu(acc + b1) -> LDS bf16.  D layout: col=lane&15, row=(lane>>4)*4+r
    #pragma unroll
    for (int j = 0; j < 4; ++j) {
        int col = wc * 64 + j * 16 + l15;
        float bb = b1[col];
        #pragma unroll
        for (int i = 0; i < 4; ++i) {
            #pragma unroll
            for (int r = 0; r < 4; ++r) {
                int row = (wr * 4 + i) * 16 + (lane >> 4) * 4 + r;
                Hbuf[row][col] = f2bf(fmaxf(acc[i][j][r] + bb, 0.f));
            }
        }
    }
    __syncthreads();

    // early-issue GEMM2' chunk-0 staging (Wf -> WTb[0]); overlaps the softmax phases
    float rf2[16];
    #pragma unroll
    for (int it = 0; it < 16; ++it) {
        int fl = tid + it * 512;
        rf2[it] = Wf[(fl >> 8) * 257 + (fl & 255)];
    }
    #pragma unroll
    for (int it = 0; it < 16; ++it) {
        int fl = tid + it * 512;
        WTb[0][fl & 255][fl >> 8] = f2bf(rf2[it]);
    }

    // ========== link column: lc_k = h_k . Wf[:,256]  (wave wid owns position wid) ==========
    float wl0 = Wf[(lane * 4 + 0) * 257 + 256];
    float wl1 = Wf[(lane * 4 + 1) * 257 + 256];
    float wl2 = Wf[(lane * 4 + 2) * 257 + 256];
    float wl3 = Wf[(lane * 4 + 3) * 257 + 256];
    float bf256 = bfv[256];

    float lcreg = 0.f;
    for (int k = 0; k < 16; ++k) {
        ushort4 hv = *(const ushort4*)&Hbuf[wid * 16 + k][lane * 4];
        float p = bf2f(hv.x) * wl0 + bf2f(hv.y) * wl1 + bf2f(hv.z) * wl2 + bf2f(hv.w) * wl3;
        #pragma unroll
        for (int off = 32; off > 0; off >>= 1) p += __shfl_xor(p, off, 64);
        if (lane == k) lcreg = p;
    }

    // ========== weights: w_k, ww_k = w_k*m_k, s, updates_256 ==========
    float wwreg = 0.f;
    float u256 = 0.f;
    if (lane < 16) {
        float mv  = mg[(blk * 8 + wid) * 16 + lane];
        float raw = lcreg + bf256;
        float sg  = 1.f / (1.f + expf(-raw));
        float v   = mv * sg;
        float lw  = v + 1e-8f;
        float nrm = lw;
        #pragma unroll
        for (int off = 8; off > 0; off >>= 1) nrm += __shfl_xor(nrm, off, 16);
        float wk = lw / nrm;
        wwreg = wk * mv;
        float u = wk * v;
        float s = wwreg;
        #pragma unroll
        for (int off = 8; off > 0; off >>= 1) {
            u += __shfl_xor(u, off, 16);
            s += __shfl_xor(s, off, 16);
        }
        u256 = u;
        if (lane == 0) sbuf[wid] = s;
    }
    u256 = __shfl(u256, 0, 64);   // broadcast to all 64 lanes of this wave

    // ========== g_p = sum_k ww_k * h_k  -> gbuf (bf16), rows 8..15 zero ==========
    {
        float ga0 = 0.f, ga1 = 0.f, ga2 = 0.f, ga3 = 0.f;
        #pragma unroll
        for (int k = 0; k < 16; ++k) {
            float wwk = __shfl(wwreg, k, 64);
            ushort4 hv = *(const ushort4*)&Hbuf[wid * 16 + k][lane * 4];
            ga0 += wwk * bf2f(hv.x);
            ga1 += wwk * bf2f(hv.y);
            ga2 += wwk * bf2f(hv.z);
            ga3 += wwk * bf2f(hv.w);
        }
        ushort4 gw; gw.x = f2bf(ga0); gw.y = f2bf(ga1); gw.z = f2bf(ga2); gw.w = f2bf(ga3);
        *(ushort4*)&gbuf[wid][lane * 4] = gw;
        ushort4 z4; z4.x = 0; z4.y = 0; z4.z = 0; z4.w = 0;
        *(ushort4*)&gbuf[8 + wid][lane * 4] = z4;
    }
    __syncthreads();   // gbuf + WTb[0] ready

    // ========== GEMM2': updates[:, :256] = g @ Wf[:, :256] (+ s*bf later) ==========
    f32x4 acc2[2];
    acc2[0] = zero4; acc2[1] = zero4;
    for (int c2 = 0; c2 < 8; ++c2) {
        const int cur = c2 & 1;
        if (c2 < 7) {
            #pragma unroll
            for (int it = 0; it < 16; ++it) {
                int fl = tid + it * 512;
                rf2[it] = Wf[((c2 + 1) * 32 + (fl >> 8)) * 257 + (fl & 255)];
            }
        }
        s16x8 ga = *(const s16x8*)&gbuf[l15][c2 * 32 + g8];
        #pragma unroll
        for (int t = 0; t < 2; ++t) {
            s16x8 bw = *(const s16x8*)&WTb[cur][(wid * 2 + t) * 16 + l15][g8];
            acc2[t] = __builtin_amdgcn_mfma_f32_16x16x32_bf16(ga, bw, acc2[t], 0, 0, 0);
        }
        if (c2 < 7) {
            #pragma unroll
            for (int it = 0; it < 16; ++it) {
                int fl = tid + it * 512;
                WTb[cur ^ 1][fl & 255][fl >> 8] = f2bf(rf2[it]);
            }
        }
        __syncthreads();
    }

    // updates -> LDS (rows 0..7 valid)
    {
        int gq = lane >> 4;   // 0..3 ; D rows gq*4+r, only rows 0..7 are positions
        if (gq < 2) {
            #pragma unroll
            for (int t = 0; t < 2; ++t) {
                int col = (wid * 2 + t) * 16 + l15;
                float bfc = bfv[col];
                #pragma unroll
                for (int r = 0; r < 4; ++r) {
                    int p = gq * 4 + r;
                    updb[p][col] = acc2[t][r] + sbuf[p] * bfc;
                }
            }
        }
    }
    __syncthreads();

    // ========== embeds update + LayerNorm (wave wid owns position wid) ==========
    {
        int base = (blk * 8 + wid) * 256;
        float4 up = *(const float4*)&updb[wid][lane * 4];
        float4 em = *(const float4*)&embeds[base + lane * 4];
        float e0 = em.x + u256 * up.x;
        float e1 = em.y + u256 * up.y;
        float e2 = em.z + u256 * up.z;
        float e3 = em.w + u256 * up.w;
        float s1 = e0 + e1 + e2 + e3;
        float s2 = e0 * e0 + e1 * e1 + e2 * e2 + e3 * e3;
        #pragma unroll
        for (int off = 32; off > 0; off >>= 1) {
            s1 += __shfl_xor(s1, off, 64);
            s2 += __shfl_xor(s2, off, 64);
        }
        float mu  = s1 * (1.f / 256.f);
        float var = s2 * (1.f / 256.f) - mu * mu;
        float rs  = rsqrtf(var + 1e-5f);
        float4 gm = *(const float4*)&gam[lane * 4];
        float4 bt = *(const float4*)&bet[lane * 4];
        float4 o;
        o.x = (e0 - mu) * rs * gm.x + bt.x;
        o.y = (e1 - mu) * rs * gm.y + bt.y;
        o.z = (e2 - mu) * rs * gm.z + bt.z;
        o.w = (e3 - mu) * rs * gm.w + bt.w;
        *(float4*)&out[base + lane * 4] = o;
    }
}

extern "C" void kernel_launch(void* const* d_in, const int* in_sizes, int n_in,
                              void* d_out, int out_size, void* d_ws, size_t ws_size,
                              hipStream_t stream) {
    (void)in_sizes; (void)n_in; (void)d_ws; (void)ws_size; (void)out_size;
    const float* net_in = (const float*)d_in[0];
    const float* embeds = (const float*)d_in[1];
    const float* mg     = (const float*)d_in[2];
    const float* W1     = (const float*)d_in[3];
    const float* b1     = (const float*)d_in[4];
    const float* Wf     = (const float*)d_in[5];
    const float* bfv    = (const float*)d_in[6];
    const float* gam    = (const float*)d_in[7];
    const float* bet    = (const float*)d_in[8];
    float* outp = (float*)d_out;
    fused_embed<<<NBLK, 512, 0, stream>>>(net_in, embeds, mg, W1, b1, Wf, bfv, gam, bet, outp);
}

// Round 2
// 281.541 us; speedup vs baseline: 1.7257x; 1.7257x over previous
//
#include <hip/hip_runtime.h>

typedef short s16x8 __attribute__((ext_vector_type(8)));
typedef float f32x4 __attribute__((ext_vector_type(4)));

__device__ __forceinline__ unsigned short f2bf(float f) {
    union { float f; unsigned u; } v; v.f = f;
    return (unsigned short)((v.u + 0x7FFFu + ((v.u >> 16) & 1u)) >> 16);
}
__device__ __forceinline__ float bf2f(unsigned short h) {
    union { unsigned u; float f; } v; v.u = ((unsigned)h) << 16;
    return v.f;
}

typedef unsigned int u32;
typedef const u32 __attribute__((address_space(1))) gu32;
typedef u32 __attribute__((address_space(3))) lu32;

__device__ __forceinline__ void gload16(const void* g, void* l) {
    __builtin_amdgcn_global_load_lds((gu32*)g, (lu32*)l, 16, 0, 0);
}

#define NBLK 2048   // 16384 positions / 8 per block

// ---------- prep: W1 (512x256 f32) -> W1T bf16 [16][256][32]; Wf -> WfT bf16 [8][256][32] ----------
__global__ void prep_weights(const float* __restrict__ W1, const float* __restrict__ Wf,
                             unsigned short* __restrict__ W1T, unsigned short* __restrict__ WfT) {
    int t = blockIdx.x * 256 + threadIdx.x;      // 131072 threads
    {   // W1T[t]: t = ((c*256)+n)*32 + kk
        int c  = t >> 13;
        int n  = (t >> 5) & 255;
        int kk = t & 31;
        W1T[t] = f2bf(W1[(c * 32 + kk) * 256 + n]);
    }
    if (t < 65536) {
        int c  = t >> 13;
        int n  = (t >> 5) & 255;
        int hh = t & 31;
        WfT[t] = f2bf(Wf[(c * 32 + hh) * 257 + n]);
    }
}

__global__ __launch_bounds__(512, 2)
void fused_embed(const float* __restrict__ net_in, const float* __restrict__ embeds,
                 const float* __restrict__ mg, const float* __restrict__ W1,
                 const float* __restrict__ b1, const float* __restrict__ Wf,
                 const float* __restrict__ bfv, const float* __restrict__ gam,
                 const float* __restrict__ bet, float* __restrict__ out,
                 const unsigned short* __restrict__ W1T, const unsigned short* __restrict__ WfT)
{
    // LDS: 16384 + 32768 + 66560 + 8448 + 8448 + 32 = 132640 B
    __shared__ unsigned short Abuf[2][128][32];   // net_in chunk, bf16, unpadded (64B rows)
    __shared__ unsigned short Wbuf[2][256][32];   // W1T / WfT chunk, bf16, unpadded
    __shared__ unsigned short Hbuf[128][260];     // H = relu(A@W1+b1), bf16 (520B rows: write+read conflict-free)
    __shared__ unsigned short gbuf[16][264];      // g rows (8 used + 8 zero pad), bf16
    __shared__ float updb[8][264];                // updates (positions x 256), f32
    __shared__ float sbuf[8];                     // s_p = sum_k w_k m_k

    const int tid  = threadIdx.x;
    const int lane = tid & 63;
    const int wid  = tid >> 6;     // 0..7
    const int wr   = wid >> 2;     // 0..1
    const int wc   = wid & 3;      // 0..3
    const int l15  = lane & 15;
    const int g8   = (lane >> 4) * 8;
    const int blk  = blockIdx.x;
    const int row0 = blk * 128;

    const f32x4 zero4 = {0.f, 0.f, 0.f, 0.f};

    // ================= GEMM1: H = relu(net_in @ W1 + b1) =================
    f32x4 acc[4][4];
    #pragma unroll
    for (int i = 0; i < 4; ++i)
        #pragma unroll
        for (int j = 0; j < 4; ++j)
            acc[i][j] = zero4;

    const int ar = tid >> 2;          // A-staging row this thread owns
    const int ac = (tid & 3) * 8;     // A-staging col group (8 f32)

    // prologue: chunk 0
    {
        const float* src = &net_in[(row0 + ar) * 512 + ac];
        float4 va = *(const float4*)src;
        float4 vb = *(const float4*)(src + 4);
        #pragma unroll
        for (int it = 0; it < 2; ++it)
            gload16(W1T + (it * 512 + tid) * 8,
                    (unsigned short*)Wbuf + (it * 512 + wid * 64) * 8);
        int4 pk;
        asm("v_cvt_pk_bf16_f32 %0, %1, %2" : "=v"(pk.x) : "v"(va.x), "v"(va.y));
        asm("v_cvt_pk_bf16_f32 %0, %1, %2" : "=v"(pk.y) : "v"(va.z), "v"(va.w));
        asm("v_cvt_pk_bf16_f32 %0, %1, %2" : "=v"(pk.z) : "v"(vb.x), "v"(vb.y));
        asm("v_cvt_pk_bf16_f32 %0, %1, %2" : "=v"(pk.w) : "v"(vb.z), "v"(vb.w));
        *(int4*)&Abuf[0][ar][ac] = pk;
    }
    __syncthreads();

    for (int kc = 0; kc < 16; ++kc) {
        const int cur = kc & 1;
        float4 va, vb;
        // prefetch: issue next-chunk loads early (latency hides under MFMA)
        if (kc < 15) {
            const float* src = &net_in[(row0 + ar) * 512 + (kc + 1) * 32 + ac];
            va = *(const float4*)src;
            vb = *(const float4*)(src + 4);
            #pragma unroll
            for (int it = 0; it < 2; ++it)
                gload16(W1T + (kc + 1) * 8192 + (it * 512 + tid) * 8,
                        (unsigned short*)Wbuf[cur ^ 1] + (it * 512 + wid * 64) * 8);
        } else {
            // GEMM2 chunk-0 prefetch into Wbuf[0] (free: last W1 chunk uses Wbuf[1])
            #pragma unroll
            for (int it = 0; it < 2; ++it)
                gload16(WfT + (it * 512 + tid) * 8,
                        (unsigned short*)Wbuf[0] + (it * 512 + wid * 64) * 8);
        }
        // fragments + 16 MFMAs on current buffer
        s16x8 af[4], bfr[4];
        #pragma unroll
        for (int i = 0; i < 4; ++i)
            af[i] = *(const s16x8*)&Abuf[cur][(wr * 4 + i) * 16 + l15][g8];
        #pragma unroll
        for (int j = 0; j < 4; ++j)
            bfr[j] = *(const s16x8*)&Wbuf[cur][(wc * 4 + j) * 16 + l15][g8];
        #pragma unroll
        for (int i = 0; i < 4; ++i)
            #pragma unroll
            for (int j = 0; j < 4; ++j)
                acc[i][j] = __builtin_amdgcn_mfma_f32_16x16x32_bf16(af[i], bfr[j], acc[i][j], 0, 0, 0);
        // write next A chunk into the other buffer
        if (kc < 15) {
            int4 pk;
            asm("v_cvt_pk_bf16_f32 %0, %1, %2" : "=v"(pk.x) : "v"(va.x), "v"(va.y));
            asm("v_cvt_pk_bf16_f32 %0, %1, %2" : "=v"(pk.y) : "v"(va.z), "v"(va.w));
            asm("v_cvt_pk_bf16_f32 %0, %1, %2" : "=v"(pk.z) : "v"(vb.x), "v"(vb.y));
            asm("v_cvt_pk_bf16_f32 %0, %1, %2" : "=v"(pk.w) : "v"(vb.z), "v"(vb.w));
            *(int4*)&Abuf[cur ^ 1][ar][ac] = pk;
        }
        __syncthreads();
    }

    // epilogue: H = relu(acc + b1) -> LDS bf16.  D layout: col=lane&15, row=(lane>>4)*4+r
    #pragma unroll
    for (int j = 0; j < 4; ++j) {
        int col = wc * 64 + j * 16 + l15;
        float bb = b1[col];
        #pragma unroll
        for (int i = 0; i < 4; ++i) {
            #pragma unroll
            for (int r = 0; r < 4; ++r) {
                int row = (wr * 4 + i) * 16 + (lane >> 4) * 4 + r;
                Hbuf[row][col] = f2bf(fmaxf(acc[i][j][r] + bb, 0.f));
            }
        }
    }
    __syncthreads();

    // ========== link column: lc_k = h_k . Wf[:,256]  (wave wid owns position wid) ==========
    float wl0 = Wf[(lane * 4 + 0) * 257 + 256];
    float wl1 = Wf[(lane * 4 + 1) * 257 + 256];
    float wl2 = Wf[(lane * 4 + 2) * 257 + 256];
    float wl3 = Wf[(lane * 4 + 3) * 257 + 256];
    float bf256 = bfv[256];

    float lcreg = 0.f;
    for (int k = 0; k < 16; ++k) {
        ushort4 hv = *(const ushort4*)&Hbuf[wid * 16 + k][lane * 4];
        float p = bf2f(hv.x) * wl0 + bf2f(hv.y) * wl1 + bf2f(hv.z) * wl2 + bf2f(hv.w) * wl3;
        #pragma unroll
        for (int off = 32; off > 0; off >>= 1) p += __shfl_xor(p, off, 64);
        if (lane == k) lcreg = p;
    }

    // ========== weights: w_k, ww_k = w_k*m_k, s, updates_256 ==========
    float wwreg = 0.f;
    float u256 = 0.f;
    if (lane < 16) {
        float mv  = mg[(blk * 8 + wid) * 16 + lane];
        float raw = lcreg + bf256;
        float sg  = 1.f / (1.f + expf(-raw));
        float v   = mv * sg;
        float lw  = v + 1e-8f;
        float nrm = lw;
        #pragma unroll
        for (int off = 8; off > 0; off >>= 1) nrm += __shfl_xor(nrm, off, 16);
        float wk = lw / nrm;
        wwreg = wk * mv;
        float u = wk * v;
        float s = wwreg;
        #pragma unroll
        for (int off = 8; off > 0; off >>= 1) {
            u += __shfl_xor(u, off, 16);
            s += __shfl_xor(s, off, 16);
        }
        u256 = u;
        if (lane == 0) sbuf[wid] = s;
    }
    u256 = __shfl(u256, 0, 64);   // broadcast to all 64 lanes of this wave

    // ========== g_p = sum_k ww_k * h_k  -> gbuf (bf16), rows 8..15 zero ==========
    {
        float ga0 = 0.f, ga1 = 0.f, ga2 = 0.f, ga3 = 0.f;
        #pragma unroll
        for (int k = 0; k < 16; ++k) {
            float wwk = __shfl(wwreg, k, 64);
            ushort4 hv = *(const ushort4*)&Hbuf[wid * 16 + k][lane * 4];
            ga0 += wwk * bf2f(hv.x);
            ga1 += wwk * bf2f(hv.y);
            ga2 += wwk * bf2f(hv.z);
            ga3 += wwk * bf2f(hv.w);
        }
        ushort4 gw; gw.x = f2bf(ga0); gw.y = f2bf(ga1); gw.z = f2bf(ga2); gw.w = f2bf(ga3);
        *(ushort4*)&gbuf[wid][lane * 4] = gw;
        ushort4 z4; z4.x = 0; z4.y = 0; z4.z = 0; z4.w = 0;
        *(ushort4*)&gbuf[8 + wid][lane * 4] = z4;
    }
    __syncthreads();   // gbuf ready + WfT chunk 0 landed (barrier drains vmcnt)

    // ========== GEMM2': updates[:, :256] = g @ Wf[:, :256] (+ s*bf later) ==========
    f32x4 acc2[2];
    acc2[0] = zero4; acc2[1] = zero4;
    for (int c2 = 0; c2 < 8; ++c2) {
        const int cur = c2 & 1;
        if (c2 < 7) {
            #pragma unroll
            for (int it = 0; it < 2; ++it)
                gload16(WfT + (c2 + 1) * 8192 + (it * 512 + tid) * 8,
                        (unsigned short*)Wbuf[cur ^ 1] + (it * 512 + wid * 64) * 8);
        }
        s16x8 ga = *(const s16x8*)&gbuf[l15][c2 * 32 + g8];
        #pragma unroll
        for (int t = 0; t < 2; ++t) {
            s16x8 bw = *(const s16x8*)&Wbuf[cur][(wid * 2 + t) * 16 + l15][g8];
            acc2[t] = __builtin_amdgcn_mfma_f32_16x16x32_bf16(ga, bw, acc2[t], 0, 0, 0);
        }
        __syncthreads();
    }

    // updates -> LDS (rows 0..7 valid)
    {
        int gq = lane >> 4;   // 0..3 ; D rows gq*4+r, only rows 0..7 are positions
        if (gq < 2) {
            #pragma unroll
            for (int t = 0; t < 2; ++t) {
                int col = (wid * 2 + t) * 16 + l15;
                float bfc = bfv[col];
                #pragma unroll
                for (int r = 0; r < 4; ++r) {
                    int p = gq * 4 + r;
                    updb[p][col] = acc2[t][r] + sbuf[p] * bfc;
                }
            }
        }
    }
    __syncthreads();

    // ========== embeds update + LayerNorm (wave wid owns position wid) ==========
    {
        int base = (blk * 8 + wid) * 256;
        float4 up = *(const float4*)&updb[wid][lane * 4];
        float4 em = *(const float4*)&embeds[base + lane * 4];
        float e0 = em.x + u256 * up.x;
        float e1 = em.y + u256 * up.y;
        float e2 = em.z + u256 * up.z;
        float e3 = em.w + u256 * up.w;
        float s1 = e0 + e1 + e2 + e3;
        float s2 = e0 * e0 + e1 * e1 + e2 * e2 + e3 * e3;
        #pragma unroll
        for (int off = 32; off > 0; off >>= 1) {
            s1 += __shfl_xor(s1, off, 64);
            s2 += __shfl_xor(s2, off, 64);
        }
        float mu  = s1 * (1.f / 256.f);
        float var = s2 * (1.f / 256.f) - mu * mu;
        float rs  = rsqrtf(var + 1e-5f);
        float4 gm = *(const float4*)&gam[lane * 4];
        float4 bt = *(const float4*)&bet[lane * 4];
        float4 o;
        o.x = (e0 - mu) * rs * gm.x + bt.x;
        o.y = (e1 - mu) * rs * gm.y + bt.y;
        o.z = (e2 - mu) * rs * gm.z + bt.z;
        o.w = (e3 - mu) * rs * gm.w + bt.w;
        *(float4*)&out[base + lane * 4] = o;
    }
}

extern "C" void kernel_launch(void* const* d_in, const int* in_sizes, int n_in,
                              void* d_out, int out_size, void* d_ws, size_t ws_size,
                              hipStream_t stream) {
    (void)in_sizes; (void)n_in; (void)ws_size; (void)out_size;
    const float* net_in = (const float*)d_in[0];
    const float* embeds = (const float*)d_in[1];
    const float* mg     = (const float*)d_in[2];
    const float* W1     = (const float*)d_in[3];
    const float* b1     = (const float*)d_in[4];
    const float* Wf     = (const float*)d_in[5];
    const float* bfv    = (const float*)d_in[6];
    const float* gam    = (const float*)d_in[7];
    const float* bet    = (const float*)d_in[8];
    float* outp = (float*)d_out;

    unsigned short* W1T = (unsigned short*)d_ws;                 // 16*256*32 = 131072 elems
    unsigned short* WfT = W1T + 131072;                          //  8*256*32 =  65536 elems

    prep_weights<<<512, 256, 0, stream>>>(W1, Wf, W1T, WfT);
    fused_embed<<<NBLK, 512, 0, stream>>>(net_in, embeds, mg, W1, b1, Wf, bfv, gam, bet, outp, W1T, WfT);
}

// Round 7
// 250.578 us; speedup vs baseline: 1.9389x; 1.1236x over previous
//
#include <hip/hip_runtime.h>

typedef short s16x8 __attribute__((ext_vector_type(8)));
typedef float f32x4 __attribute__((ext_vector_type(4)));

__device__ __forceinline__ unsigned short f2bf(float f) {
    union { float f; unsigned u; } v; v.f = f;
    return (unsigned short)((v.u + 0x7FFFu + ((v.u >> 16) & 1u)) >> 16);
}
__device__ __forceinline__ float bf2f(unsigned short h) {
    union { unsigned u; float f; } v; v.u = ((unsigned)h) << 16;
    return v.f;
}

typedef unsigned int u32;
typedef const u32 __attribute__((address_space(1))) gu32;
typedef u32 __attribute__((address_space(3))) lu32;

__device__ __forceinline__ void gload16(const void* g, void* l) {
    __builtin_amdgcn_global_load_lds((gu32*)g, (lu32*)l, 16, 0, 0);
}

// LDS-only barrier: does NOT drain vmcnt, so register prefetch loads stay in
// flight across it. sched_barrier(0) fences compiler motion (rule #18),
// "memory" clobber fences IR-level motion.
__device__ __forceinline__ void wg_barrier_lds() {
    __builtin_amdgcn_sched_barrier(0);
    asm volatile("s_waitcnt lgkmcnt(0)" ::: "memory");
    __builtin_amdgcn_s_barrier();
    __builtin_amdgcn_sched_barrier(0);
}

#define NBLK 2048   // 16384 positions / 8 per block

// ---------- prep: W1 (512x256 f32) -> W1T bf16 [16][256][32]; Wf -> WfT bf16 [8][256][32] ----------
__global__ void prep_weights(const float* __restrict__ W1, const float* __restrict__ Wf,
                             unsigned short* __restrict__ W1T, unsigned short* __restrict__ WfT) {
    int t = blockIdx.x * 256 + threadIdx.x;      // 131072 threads
    {   // W1T[t]: t = ((c*256)+n)*32 + kk
        int c  = t >> 13;
        int n  = (t >> 5) & 255;
        int kk = t & 31;
        W1T[t] = f2bf(W1[(c * 32 + kk) * 256 + n]);
    }
    if (t < 65536) {
        int c  = t >> 13;
        int n  = (t >> 5) & 255;
        int hh = t & 31;
        WfT[t] = f2bf(Wf[(c * 32 + hh) * 257 + n]);
    }
}

__global__ __launch_bounds__(512, 2)
void fused_embed(const float* __restrict__ net_in, const float* __restrict__ embeds,
                 const float* __restrict__ mg, const float* __restrict__ W1,
                 const float* __restrict__ b1, const float* __restrict__ Wf,
                 const float* __restrict__ bfv, const float* __restrict__ gam,
                 const float* __restrict__ bet, float* __restrict__ out,
                 const unsigned short* __restrict__ W1T, const unsigned short* __restrict__ WfT)
{
    // LDS: 16384 + 32768 + 66560 + 8448 + 8448 + 32 = 132640 B  (1 block/CU —
    // the empirically-validated envelope: every <80KB variant failed with a
    // nondeterministic absmax; both passes ran 1 block/CU)
    __shared__ unsigned short Abuf[2][128][32];   // net_in chunk, bf16, unpadded (64B rows)
    __shared__ unsigned short Wbuf[2][256][32];   // W1T / WfT chunk, bf16, unpadded
    __shared__ unsigned short Hbuf[128][260];     // H = relu(A@W1+b1), bf16 (520B rows)
    __shared__ unsigned short gbuf[16][264];      // g rows (8 used + 8 zero pad), bf16
    __shared__ float updb[8][264];                // updates (positions x 256), f32
    __shared__ float sbuf[8];                     // s_p = sum_k w_k m_k

    const int tid  = threadIdx.x;
    const int lane = tid & 63;
    const int wid  = tid >> 6;     // 0..7
    const int wr   = wid >> 2;     // 0..1
    const int wc   = wid & 3;      // 0..3
    const int l15  = lane & 15;
    const int g8   = (lane >> 4) * 8;
    const int blk  = blockIdx.x;
    const int row0 = blk * 128;

    const f32x4 zero4 = {0.f, 0.f, 0.f, 0.f};

    // ================= GEMM1: H = relu(net_in @ W1 + b1) =================
    f32x4 acc[4][4];
    #pragma unroll
    for (int i = 0; i < 4; ++i)
        #pragma unroll
        for (int j = 0; j < 4; ++j)
            acc[i][j] = zero4;

    const int ar = tid >> 2;          // A-staging row this thread owns
    const int ac = (tid & 3) * 8;     // A-staging col group (8 f32)

    // 2-deep register prefetch slots (statically indexed only — full unroll)
    float4 vaA[2], vbA[2];
    int4   wA0[2], wA1[2];

#define G1_ISSUE(KC, S) do { \
        const float* _src = &net_in[(row0 + ar) * 512 + (KC) * 32 + ac]; \
        vaA[S] = *(const float4*)_src; \
        vbA[S] = *(const float4*)(_src + 4); \
        wA0[S] = *(const int4*)(W1T + (KC) * 8192 + tid * 8); \
        wA1[S] = *(const int4*)(W1T + (KC) * 8192 + (512 + tid) * 8); \
    } while (0)

#define G1_WRITE(KC, S) do { \
        int4 _pk; \
        asm("v_cvt_pk_bf16_f32 %0, %1, %2" : "=v"(_pk.x) : "v"(vaA[S].x), "v"(vaA[S].y)); \
        asm("v_cvt_pk_bf16_f32 %0, %1, %2" : "=v"(_pk.y) : "v"(vaA[S].z), "v"(vaA[S].w)); \
        asm("v_cvt_pk_bf16_f32 %0, %1, %2" : "=v"(_pk.z) : "v"(vbA[S].x), "v"(vbA[S].y)); \
        asm("v_cvt_pk_bf16_f32 %0, %1, %2" : "=v"(_pk.w) : "v"(vbA[S].z), "v"(vbA[S].w)); \
        *(int4*)&Abuf[(KC) & 1][ar][ac] = _pk; \
        *(int4*)((unsigned short*)Wbuf[(KC) & 1] + tid * 8) = wA0[S]; \
        *(int4*)((unsigned short*)Wbuf[(KC) & 1] + (512 + tid) * 8) = wA1[S]; \
    } while (0)

    // prologue: chunks 0 and 1 in flight; chunk 0 written
    G1_ISSUE(0, 0);
    G1_ISSUE(1, 1);
    G1_WRITE(0, 0);
    wg_barrier_lds();

    #pragma unroll
    for (int kc = 0; kc < 16; ++kc) {
        const int cur = kc & 1;
        // issue chunk kc+2 into the slot just freed by chunk kc's write (at kc-1)
        if (kc < 14) G1_ISSUE(kc + 2, kc & 1);
        // GEMM2 chunk-0 prefetch into Wbuf[0] (kc==15 reads Wbuf[1]; drained by
        // the full __syncthreads after the epilogue, long before GEMM2 reads it)
        if (kc == 15) {
            gload16(WfT + tid * 8, (unsigned short*)Wbuf + (wid * 64) * 8);
            gload16(WfT + (512 + tid) * 8, (unsigned short*)Wbuf + ((512 + wid * 64)) * 8);
        }
        // write chunk kc+1 (loads issued at kc-1 -> one full iteration of cover)
        if (kc < 15) G1_WRITE(kc + 1, (kc + 1) & 1);
        // fragments + 16 MFMAs on current buffer
        s16x8 af[4], bfr[4];
        #pragma unroll
        for (int i = 0; i < 4; ++i)
            af[i] = *(const s16x8*)&Abuf[cur][(wr * 4 + i) * 16 + l15][g8];
        #pragma unroll
        for (int j = 0; j < 4; ++j)
            bfr[j] = *(const s16x8*)&Wbuf[cur][(wc * 4 + j) * 16 + l15][g8];
        #pragma unroll
        for (int i = 0; i < 4; ++i)
            #pragma unroll
            for (int j = 0; j < 4; ++j)
                acc[i][j] = __builtin_amdgcn_mfma_f32_16x16x32_bf16(af[i], bfr[j], acc[i][j], 0, 0, 0);
        wg_barrier_lds();
    }
#undef G1_ISSUE
#undef G1_WRITE

    // epilogue: H = relu(acc + b1) -> LDS bf16.  D layout: col=lane&15, row=(lane>>4)*4+r
    #pragma unroll
    for (int j = 0; j < 4; ++j) {
        int col = wc * 64 + j * 16 + l15;
        float bb = b1[col];
        #pragma unroll
        for (int i = 0; i < 4; ++i) {
            #pragma unroll
            for (int r = 0; r < 4; ++r) {
                int row = (wr * 4 + i) * 16 + (lane >> 4) * 4 + r;
                Hbuf[row][col] = f2bf(fmaxf(acc[i][j][r] + bb, 0.f));
            }
        }
    }
    __syncthreads();   // full barrier: Hbuf visible AND kc==15 WfT DMA drained

    // ========== link column: lc_k = h_k . Wf[:,256]  (wave wid owns position wid) ==========
    float wl0 = Wf[(lane * 4 + 0) * 257 + 256];
    float wl1 = Wf[(lane * 4 + 1) * 257 + 256];
    float wl2 = Wf[(lane * 4 + 2) * 257 + 256];
    float wl3 = Wf[(lane * 4 + 3) * 257 + 256];
    float bf256 = bfv[256];

    float lcreg = 0.f;
    for (int k = 0; k < 16; ++k) {
        ushort4 hv = *(const ushort4*)&Hbuf[wid * 16 + k][lane * 4];
        float p = bf2f(hv.x) * wl0 + bf2f(hv.y) * wl1 + bf2f(hv.z) * wl2 + bf2f(hv.w) * wl3;
        #pragma unroll
        for (int off = 32; off > 0; off >>= 1) p += __shfl_xor(p, off, 64);
        if (lane == k) lcreg = p;
    }

    // ========== weights: w_k, ww_k = w_k*m_k, s, updates_256 ==========
    float wwreg = 0.f;
    float u256 = 0.f;
    if (lane < 16) {
        float mv  = mg[(blk * 8 + wid) * 16 + lane];
        float raw = lcreg + bf256;
        float sg  = 1.f / (1.f + expf(-raw));
        float v   = mv * sg;
        float lw  = v + 1e-8f;
        float nrm = lw;
        #pragma unroll
        for (int off = 8; off > 0; off >>= 1) nrm += __shfl_xor(nrm, off, 16);
        float wk = lw / nrm;
        wwreg = wk * mv;
        float u = wk * v;
        float s = wwreg;
        #pragma unroll
        for (int off = 8; off > 0; off >>= 1) {
            u += __shfl_xor(u, off, 16);
            s += __shfl_xor(s, off, 16);
        }
        u256 = u;
        if (lane == 0) sbuf[wid] = s;
    }
    u256 = __shfl(u256, 0, 64);   // broadcast to all 64 lanes of this wave

    // ========== g_p = sum_k ww_k * h_k  -> gbuf (bf16), rows 8..15 zero ==========
    {
        float ga0 = 0.f, ga1 = 0.f, ga2 = 0.f, ga3 = 0.f;
        #pragma unroll
        for (int k = 0; k < 16; ++k) {
            float wwk = __shfl(wwreg, k, 64);
            ushort4 hv = *(const ushort4*)&Hbuf[wid * 16 + k][lane * 4];
            ga0 += wwk * bf2f(hv.x);
            ga1 += wwk * bf2f(hv.y);
            ga2 += wwk * bf2f(hv.z);
            ga3 += wwk * bf2f(hv.w);
        }
        ushort4 gw; gw.x = f2bf(ga0); gw.y = f2bf(ga1); gw.z = f2bf(ga2); gw.w = f2bf(ga3);
        *(ushort4*)&gbuf[wid][lane * 4] = gw;
        ushort4 z4; z4.x = 0; z4.y = 0; z4.z = 0; z4.w = 0;
        *(ushort4*)&gbuf[8 + wid][lane * 4] = z4;
    }
    __syncthreads();   // gbuf ready; WfT chunk 0 already landed

    // ========== GEMM2': updates[:, :256] = g @ Wf[:, :256] (+ s*bf later) ==========
    f32x4 acc2[2];
    acc2[0] = zero4; acc2[1] = zero4;
    for (int c2 = 0; c2 < 8; ++c2) {
        const int cur = c2 & 1;
        if (c2 < 7) {
            #pragma unroll
            for (int it = 0; it < 2; ++it)
                gload16(WfT + (c2 + 1) * 8192 + (it * 512 + tid) * 8,
                        (unsigned short*)Wbuf[cur ^ 1] + (it * 512 + wid * 64) * 8);
        }
        s16x8 ga = *(const s16x8*)&gbuf[l15][c2 * 32 + g8];
        #pragma unroll
        for (int t = 0; t < 2; ++t) {
            s16x8 bw = *(const s16x8*)&Wbuf[cur][(wid * 2 + t) * 16 + l15][g8];
            acc2[t] = __builtin_amdgcn_mfma_f32_16x16x32_bf16(ga, bw, acc2[t], 0, 0, 0);
        }
        __syncthreads();
    }

    // updates -> LDS (rows 0..7 valid)
    {
        int gq = lane >> 4;   // 0..3 ; D rows gq*4+r, only rows 0..7 are positions
        if (gq < 2) {
            #pragma unroll
            for (int t = 0; t < 2; ++t) {
                int col = (wid * 2 + t) * 16 + l15;
                float bfc = bfv[col];
                #pragma unroll
                for (int r = 0; r < 4; ++r) {
                    int p = gq * 4 + r;
                    updb[p][col] = acc2[t][r] + sbuf[p] * bfc;
                }
            }
        }
    }
    __syncthreads();

    // ========== embeds update + LayerNorm (wave wid owns position wid) ==========
    {
        int base = (blk * 8 + wid) * 256;
        float4 up = *(const float4*)&updb[wid][lane * 4];
        float4 em = *(const float4*)&embeds[base + lane * 4];
        float e0 = em.x + u256 * up.x;
        float e1 = em.y + u256 * up.y;
        float e2 = em.z + u256 * up.z;
        float e3 = em.w + u256 * up.w;
        float s1 = e0 + e1 + e2 + e3;
        float s2 = e0 * e0 + e1 * e1 + e2 * e2 + e3 * e3;
        #pragma unroll
        for (int off = 32; off > 0; off >>= 1) {
            s1 += __shfl_xor(s1, off, 64);
            s2 += __shfl_xor(s2, off, 64);
        }
        float mu  = s1 * (1.f / 256.f);
        float var = s2 * (1.f / 256.f) - mu * mu;
        float rs  = rsqrtf(var + 1e-5f);
        float4 gm = *(const float4*)&gam[lane * 4];
        float4 bt = *(const float4*)&bet[lane * 4];
        float4 o;
        o.x = (e0 - mu) * rs * gm.x + bt.x;
        o.y = (e1 - mu) * rs * gm.y + bt.y;
        o.z = (e2 - mu) * rs * gm.z + bt.z;
        o.w = (e3 - mu) * rs * gm.w + bt.w;
        *(float4*)&out[base + lane * 4] = o;
    }
}

extern "C" void kernel_launch(void* const* d_in, const int* in_sizes, int n_in,
                              void* d_out, int out_size, void* d_ws, size_t ws_size,
                              hipStream_t stream) {
    (void)in_sizes; (void)n_in; (void)ws_size; (void)out_size;
    const float* net_in = (const float*)d_in[0];
    const float* embeds = (const float*)d_in[1];
    const float* mg     = (const float*)d_in[2];
    const float* W1     = (const float*)d_in[3];
    const float* b1     = (const float*)d_in[4];
    const float* Wf     = (const float*)d_in[5];
    const float* bfv    = (const float*)d_in[6];
    const float* gam    = (const float*)d_in[7];
    const float* bet    = (const float*)d_in[8];
    float* outp = (float*)d_out;

    unsigned short* W1T = (unsigned short*)d_ws;                 // 16*256*32 = 131072 elems
    unsigned short* WfT = W1T + 131072;                          //  8*256*32 =  65536 elems

    prep_weights<<<512, 256, 0, stream>>>(W1, Wf, W1T, WfT);
    fused_embed<<<NBLK, 512, 0, stream>>>(net_in, embeds, mg, W1, b1, Wf, bfv, gam, bet, outp, W1T, WfT);
}

// Round 8
// 203.755 us; speedup vs baseline: 2.3845x; 1.2298x over previous
//
#include <hip/hip_runtime.h>

typedef short s16x8 __attribute__((ext_vector_type(8)));
typedef float f32x4 __attribute__((ext_vector_type(4)));

__device__ __forceinline__ unsigned short f2bf(float f) {
    union { float f; unsigned u; } v; v.f = f;
    return (unsigned short)((v.u + 0x7FFFu + ((v.u >> 16) & 1u)) >> 16);
}
__device__ __forceinline__ float bf2f(unsigned short h) {
    union { unsigned u; float f; } v; v.u = ((unsigned)h) << 16;
    return v.f;
}

// LDS-only barrier: does NOT drain vmcnt, so register prefetch loads stay in
// flight across it. sched_barrier(0) fences compiler motion (rule #18),
// "memory" clobber fences IR-level motion.
__device__ __forceinline__ void wg_barrier_lds() {
    __builtin_amdgcn_sched_barrier(0);
    asm volatile("s_waitcnt lgkmcnt(0)" ::: "memory");
    __builtin_amdgcn_s_barrier();
    __builtin_amdgcn_sched_barrier(0);
}

#define NBLK 2048   // 16384 positions / 8 per block

// ---------- prep: W1 (512x256 f32) -> W1T bf16 [16][256][32]; Wf -> WfT bf16 [8][256][32] ----------
__global__ void prep_weights(const float* __restrict__ W1, const float* __restrict__ Wf,
                             unsigned short* __restrict__ W1T, unsigned short* __restrict__ WfT) {
    int t = blockIdx.x * 256 + threadIdx.x;      // 131072 threads
    {   // W1T[t]: t = ((c*256)+n)*32 + kk
        int c  = t >> 13;
        int n  = (t >> 5) & 255;
        int kk = t & 31;
        W1T[t] = f2bf(W1[(c * 32 + kk) * 256 + n]);
    }
    if (t < 65536) {
        int c  = t >> 13;
        int n  = (t >> 5) & 255;
        int hh = t & 31;
        WfT[t] = f2bf(Wf[(c * 32 + hh) * 257 + n]);
    }
}

__global__ __launch_bounds__(512, 2)
void fused_embed(const float* __restrict__ net_in, const float* __restrict__ embeds,
                 const float* __restrict__ mg, const float* __restrict__ W1,
                 const float* __restrict__ b1, const float* __restrict__ Wf,
                 const float* __restrict__ bfv, const float* __restrict__ gam,
                 const float* __restrict__ bet, float* __restrict__ out,
                 const unsigned short* __restrict__ W1T, const unsigned short* __restrict__ WfT)
{
    // LDS: 16384 + 66560 + 8448 + 8448 + 32 = 99872 B -> 1 block/CU (the
    // validated envelope: 1-block passed 3/3 deterministic, 2-block failed 4/4).
    // W1T/WfT are NOT staged in LDS: they are L2-resident (384 KB total shared
    // by all blocks) and stream straight into MFMA B-fragment registers.
    __shared__ unsigned short Abuf[2][128][32];   // net_in chunk, bf16, unpadded (64B rows)
    __shared__ unsigned short Hbuf[128][260];     // H = relu(A@W1+b1), bf16 (520B rows)
    __shared__ unsigned short gbuf[16][264];      // g rows (8 used + 8 zero pad), bf16
    __shared__ float updb[8][264];                // updates (positions x 256), f32
    __shared__ float sbuf[8];                     // s_p = sum_k w_k m_k

    const int tid  = threadIdx.x;
    const int lane = tid & 63;
    const int wid  = tid >> 6;     // 0..7
    const int wr   = wid >> 2;     // 0..1
    const int wc   = wid & 3;      // 0..3
    const int l15  = lane & 15;
    const int g8   = (lane >> 4) * 8;
    const int blk  = blockIdx.x;
    const int row0 = blk * 128;

    const f32x4 zero4 = {0.f, 0.f, 0.f, 0.f};

    // ================= GEMM1: H = relu(net_in @ W1 + b1) =================
    f32x4 acc[4][4];
    #pragma unroll
    for (int i = 0; i < 4; ++i)
        #pragma unroll
        for (int j = 0; j < 4; ++j)
            acc[i][j] = zero4;

    const int ar = tid >> 2;          // A-staging row this thread owns
    const int ac = (tid & 3) * 8;     // A-staging col group (8 f32)
    const int wn = (wc * 64 + l15) * 32 + g8;   // W-fragment base offset (shorts) within a chunk

    // 2-deep register prefetch slots (statically indexed only — full unroll)
    float4 vaA[2], vbA[2];            // A: this thread's 8 f32
    s16x8  wW0[2], wW1[2], wW2[2], wW3[2];   // W: this lane's 4 B-fragments (16B each, L2)

#define G1_ISSUE(KC, S) do { \
        const float* _src = &net_in[(row0 + ar) * 512 + (KC) * 32 + ac]; \
        vaA[S] = *(const float4*)_src; \
        vbA[S] = *(const float4*)(_src + 4); \
        const unsigned short* _wp = W1T + (KC) * 8192 + wn; \
        wW0[S] = *(const s16x8*)(_wp); \
        wW1[S] = *(const s16x8*)(_wp + 512); \
        wW2[S] = *(const s16x8*)(_wp + 1024); \
        wW3[S] = *(const s16x8*)(_wp + 1536); \
    } while (0)

#define G1_WRITE(KC, S) do { \
        int4 _pk; \
        asm("v_cvt_pk_bf16_f32 %0, %1, %2" : "=v"(_pk.x) : "v"(vaA[S].x), "v"(vaA[S].y)); \
        asm("v_cvt_pk_bf16_f32 %0, %1, %2" : "=v"(_pk.y) : "v"(vaA[S].z), "v"(vaA[S].w)); \
        asm("v_cvt_pk_bf16_f32 %0, %1, %2" : "=v"(_pk.z) : "v"(vbA[S].x), "v"(vbA[S].y)); \
        asm("v_cvt_pk_bf16_f32 %0, %1, %2" : "=v"(_pk.w) : "v"(vbA[S].z), "v"(vbA[S].w)); \
        *(int4*)&Abuf[(KC) & 1][ar][ac] = _pk; \
    } while (0)

    // prologue: chunks 0 and 1 in flight; chunk 0's A written
    G1_ISSUE(0, 0);
    G1_ISSUE(1, 1);
    G1_WRITE(0, 0);
    wg_barrier_lds();

    #pragma unroll
    for (int kc = 0; kc < 16; ++kc) {
        const int cur = kc & 1;
        // consume current W slot into locals BEFORE reissuing it (SSA hygiene)
        s16x8 b0 = wW0[cur], b1 = wW1[cur], b2 = wW2[cur], b3 = wW3[cur];
        // issue chunk kc+2 into the slot just freed
        if (kc < 14) G1_ISSUE(kc + 2, cur);
        // write chunk kc+1's A (loads issued at kc-1 -> a full iteration of cover)
        if (kc < 15) G1_WRITE(kc + 1, (kc + 1) & 1);
        // A fragments + 16 MFMAs on current buffer
        s16x8 af[4];
        #pragma unroll
        for (int i = 0; i < 4; ++i)
            af[i] = *(const s16x8*)&Abuf[cur][(wr * 4 + i) * 16 + l15][g8];
        #pragma unroll
        for (int i = 0; i < 4; ++i) {
            acc[i][0] = __builtin_amdgcn_mfma_f32_16x16x32_bf16(af[i], b0, acc[i][0], 0, 0, 0);
            acc[i][1] = __builtin_amdgcn_mfma_f32_16x16x32_bf16(af[i], b1, acc[i][1], 0, 0, 0);
            acc[i][2] = __builtin_amdgcn_mfma_f32_16x16x32_bf16(af[i], b2, acc[i][2], 0, 0, 0);
            acc[i][3] = __builtin_amdgcn_mfma_f32_16x16x32_bf16(af[i], b3, acc[i][3], 0, 0, 0);
        }
        wg_barrier_lds();
    }
#undef G1_ISSUE
#undef G1_WRITE

    // epilogue: H = relu(acc + b1) -> LDS bf16.  D layout: col=lane&15, row=(lane>>4)*4+r
    #pragma unroll
    for (int j = 0; j < 4; ++j) {
        int col = wc * 64 + j * 16 + l15;
        float bb = b1[col];
        #pragma unroll
        for (int i = 0; i < 4; ++i) {
            #pragma unroll
            for (int r = 0; r < 4; ++r) {
                int row = (wr * 4 + i) * 16 + (lane >> 4) * 4 + r;
                Hbuf[row][col] = f2bf(fmaxf(acc[i][j][r] + bb, 0.f));
            }
        }
    }
    __syncthreads();   // Hbuf visible to all waves

    // ========== link column: lc_k = h_k . Wf[:,256]  (wave wid owns position wid) ==========
    float wl0 = Wf[(lane * 4 + 0) * 257 + 256];
    float wl1 = Wf[(lane * 4 + 1) * 257 + 256];
    float wl2 = Wf[(lane * 4 + 2) * 257 + 256];
    float wl3 = Wf[(lane * 4 + 3) * 257 + 256];
    float bf256 = bfv[256];

    float lcreg = 0.f;
    for (int k = 0; k < 16; ++k) {
        ushort4 hv = *(const ushort4*)&Hbuf[wid * 16 + k][lane * 4];
        float p = bf2f(hv.x) * wl0 + bf2f(hv.y) * wl1 + bf2f(hv.z) * wl2 + bf2f(hv.w) * wl3;
        #pragma unroll
        for (int off = 32; off > 0; off >>= 1) p += __shfl_xor(p, off, 64);
        if (lane == k) lcreg = p;
    }

    // ========== weights: w_k, ww_k = w_k*m_k, s, updates_256 ==========
    float wwreg = 0.f;
    float u256 = 0.f;
    if (lane < 16) {
        float mv  = mg[(blk * 8 + wid) * 16 + lane];
        float raw = lcreg + bf256;
        float sg  = 1.f / (1.f + expf(-raw));
        float v   = mv * sg;
        float lw  = v + 1e-8f;
        float nrm = lw;
        #pragma unroll
        for (int off = 8; off > 0; off >>= 1) nrm += __shfl_xor(nrm, off, 16);
        float wk = lw / nrm;
        wwreg = wk * mv;
        float u = wk * v;
        float s = wwreg;
        #pragma unroll
        for (int off = 8; off > 0; off >>= 1) {
            u += __shfl_xor(u, off, 16);
            s += __shfl_xor(s, off, 16);
        }
        u256 = u;
        if (lane == 0) sbuf[wid] = s;
    }
    u256 = __shfl(u256, 0, 64);   // broadcast to all 64 lanes of this wave

    // ========== g_p = sum_k ww_k * h_k  -> gbuf (bf16), rows 8..15 zero ==========
    {
        float ga0 = 0.f, ga1 = 0.f, ga2 = 0.f, ga3 = 0.f;
        #pragma unroll
        for (int k = 0; k < 16; ++k) {
            float wwk = __shfl(wwreg, k, 64);
            ushort4 hv = *(const ushort4*)&Hbuf[wid * 16 + k][lane * 4];
            ga0 += wwk * bf2f(hv.x);
            ga1 += wwk * bf2f(hv.y);
            ga2 += wwk * bf2f(hv.z);
            ga3 += wwk * bf2f(hv.w);
        }
        ushort4 gw; gw.x = f2bf(ga0); gw.y = f2bf(ga1); gw.z = f2bf(ga2); gw.w = f2bf(ga3);
        *(ushort4*)&gbuf[wid][lane * 4] = gw;
        ushort4 z4; z4.x = 0; z4.y = 0; z4.z = 0; z4.w = 0;
        *(ushort4*)&gbuf[8 + wid][lane * 4] = z4;
    }
    __syncthreads();   // gbuf ready

    // ========== GEMM2': updates[:, :256] = g @ Wf[:, :256] — B from L2, ZERO barriers ==========
    f32x4 acc2[2];
    acc2[0] = zero4; acc2[1] = zero4;
    {
        const int w2n0 = ((wid * 2 + 0) * 16 + l15) * 32 + g8;
        const int w2n1 = ((wid * 2 + 1) * 16 + l15) * 32 + g8;
        s16x8 w2a[2], w2b[2];
        w2a[0] = *(const s16x8*)(WfT + w2n0);
        w2b[0] = *(const s16x8*)(WfT + w2n1);
        #pragma unroll
        for (int c2 = 0; c2 < 8; ++c2) {
            const int cur = c2 & 1;
            s16x8 ba = w2a[cur], bb = w2b[cur];
            if (c2 < 7) {
                w2a[cur ^ 1] = *(const s16x8*)(WfT + (c2 + 1) * 8192 + w2n0);
                w2b[cur ^ 1] = *(const s16x8*)(WfT + (c2 + 1) * 8192 + w2n1);
            }
            s16x8 ga = *(const s16x8*)&gbuf[l15][c2 * 32 + g8];
            acc2[0] = __builtin_amdgcn_mfma_f32_16x16x32_bf16(ga, ba, acc2[0], 0, 0, 0);
            acc2[1] = __builtin_amdgcn_mfma_f32_16x16x32_bf16(ga, bb, acc2[1], 0, 0, 0);
        }
    }

    // updates -> LDS (rows 0..7 valid)
    {
        int gq = lane >> 4;   // 0..3 ; D rows gq*4+r, only rows 0..7 are positions
        if (gq < 2) {
            #pragma unroll
            for (int t = 0; t < 2; ++t) {
                int col = (wid * 2 + t) * 16 + l15;
                float bfc = bfv[col];
                #pragma unroll
                for (int r = 0; r < 4; ++r) {
                    int p = gq * 4 + r;
                    updb[p][col] = acc2[t][r] + sbuf[p] * bfc;
                }
            }
        }
    }
    __syncthreads();

    // ========== embeds update + LayerNorm (wave wid owns position wid) ==========
    {
        int base = (blk * 8 + wid) * 256;
        float4 up = *(const float4*)&updb[wid][lane * 4];
        float4 em = *(const float4*)&embeds[base + lane * 4];
        float e0 = em.x + u256 * up.x;
        float e1 = em.y + u256 * up.y;
        float e2 = em.z + u256 * up.z;
        float e3 = em.w + u256 * up.w;
        float s1 = e0 + e1 + e2 + e3;
        float s2 = e0 * e0 + e1 * e1 + e2 * e2 + e3 * e3;
        #pragma unroll
        for (int off = 32; off > 0; off >>= 1) {
            s1 += __shfl_xor(s1, off, 64);
            s2 += __shfl_xor(s2, off, 64);
        }
        float mu  = s1 * (1.f / 256.f);
        float var = s2 * (1.f / 256.f) - mu * mu;
        float rs  = rsqrtf(var + 1e-5f);
        float4 gm = *(const float4*)&gam[lane * 4];
        float4 bt = *(const float4*)&bet[lane * 4];
        float4 o;
        o.x = (e0 - mu) * rs * gm.x + bt.x;
        o.y = (e1 - mu) * rs * gm.y + bt.y;
        o.z = (e2 - mu) * rs * gm.z + bt.z;
        o.w = (e3 - mu) * rs * gm.w + bt.w;
        *(float4*)&out[base + lane * 4] = o;
    }
}

extern "C" void kernel_launch(void* const* d_in, const int* in_sizes, int n_in,
                              void* d_out, int out_size, void* d_ws, size_t ws_size,
                              hipStream_t stream) {
    (void)in_sizes; (void)n_in; (void)ws_size; (void)out_size;
    const float* net_in = (const float*)d_in[0];
    const float* embeds = (const float*)d_in[1];
    const float* mg     = (const float*)d_in[2];
    const float* W1     = (const float*)d_in[3];
    const float* b1     = (const float*)d_in[4];
    const float* Wf     = (const float*)d_in[5];
    const float* bfv    = (const float*)d_in[6];
    const float* gam    = (const float*)d_in[7];
    const float* bet    = (const float*)d_in[8];
    float* outp = (float*)d_out;

    unsigned short* W1T = (unsigned short*)d_ws;                 // 16*256*32 = 131072 elems
    unsigned short* WfT = W1T + 131072;                          //  8*256*32 =  65536 elems

    prep_weights<<<512, 256, 0, stream>>>(W1, Wf, W1T, WfT);
    fused_embed<<<NBLK, 512, 0, stream>>>(net_in, embeds, mg, W1, b1, Wf, bfv, gam, bet, outp, W1T, WfT);
}